// Round 10
// baseline (2333.115 us; speedup 1.0000x reference)
//
#include <hip/hip_runtime.h>
#include <hip/hip_fp16.h>
#include <math.h>

#define B_ 64
#define T_ 512

typedef _Float16 h2_t __attribute__((ext_vector_type(2)));

__device__ __forceinline__ float fdot2u(unsigned int a, unsigned int b, float c) {
#if __has_builtin(__builtin_amdgcn_fdot2)
    return __builtin_amdgcn_fdot2(__builtin_bit_cast(h2_t, a),
                                  __builtin_bit_cast(h2_t, b), c, false);
#else
    const __half2 ah = __builtin_bit_cast(__half2, a);
    const __half2 bh = __builtin_bit_cast(__half2, b);
    const float2 af = __half22float2(ah), bf = __half22float2(bh);
    return c + af.x * bf.x + af.y * bf.y;
#endif
}
__device__ __forceinline__ unsigned int pack_h2(float x, float y) {
    const __half2 h = __float22half2_rn(make_float2(x, y));
    return __builtin_bit_cast(unsigned int, h);
}
__device__ __forceinline__ float ubits(unsigned int a) { return __builtin_bit_cast(float, a); }
__device__ __forceinline__ unsigned short f2h_bits(float x) {
    return __builtin_bit_cast(unsigned short, (_Float16)x);
}

__device__ __forceinline__ float fsig(float z) { return 1.f / (1.f + __expf(-z)); }
__device__ __forceinline__ float ftanh(float z) {
    const float e = __expf(2.f * z);
    return 1.f - 2.f / (e + 1.f);
}

// LDS-only barrier: lgkmcnt(0) + s_barrier, no vmcnt drain (v12-proven).
__device__ __forceinline__ void bar_lds() {
    asm volatile("s_waitcnt lgkmcnt(0)" ::: "memory");
    __builtin_amdgcn_s_barrier();
    asm volatile("" ::: "memory");
}

// ---------------------------------------------------------------------------
// GEMM v2 (unchanged): C[M,N] = (A*mask)@W + bias, packed-fp16 dot2.
// ---------------------------------------------------------------------------
__global__ __launch_bounds__(256) void gemm_mask_f16(
    const float* __restrict__ A, const float* __restrict__ W,
    const float* __restrict__ bias, const float* __restrict__ mask,
    float* __restrict__ C, int M, int N, int K)
{
    const int TM = 64, TN = 64, TK = 32, KP = 16;
    __shared__ __align__(16) unsigned int As2[KP][68];
    __shared__ __align__(16) unsigned int Bs2[KP][68];

    const int tid = threadIdx.x;
    const int bn = blockIdx.x;
    const int bm = blockIdx.y;
    const int row0 = bm * TM;
    const int b = row0 / T_;

    const int ty = tid >> 4;
    const int tx = tid & 15;
    const int m0 = ty * 4;
    const int n0 = tx * 4;

    float acc[4][4];
#pragma unroll
    for (int i = 0; i < 4; i++)
#pragma unroll
        for (int j = 0; j < 4; j++) acc[i][j] = 0.f;

    for (int kk = 0; kk < K; kk += TK) {
        {
            const int m = tid >> 2;
            const int kq = (tid & 3) * 8;
            const float4 mv0 = *(const float4*)(mask + (size_t)b * K + kk + kq);
            const float4 mv1 = *(const float4*)(mask + (size_t)b * K + kk + kq + 4);
            const float4 a0 = *(const float4*)(A + (size_t)(row0 + m) * K + kk + kq);
            const float4 a1 = *(const float4*)(A + (size_t)(row0 + m) * K + kk + kq + 4);
            As2[kq / 2 + 0][m] = pack_h2(a0.x * mv0.x, a0.y * mv0.y);
            As2[kq / 2 + 1][m] = pack_h2(a0.z * mv0.z, a0.w * mv0.w);
            As2[kq / 2 + 2][m] = pack_h2(a1.x * mv1.x, a1.y * mv1.y);
            As2[kq / 2 + 3][m] = pack_h2(a1.z * mv1.z, a1.w * mv1.w);
        }
        {
            const int kp = tid >> 4;
            const int nq = (tid & 15) * 4;
            const float4 w0 = *(const float4*)(W + (size_t)(kk + 2 * kp) * N + bn * TN + nq);
            const float4 w1 = *(const float4*)(W + (size_t)(kk + 2 * kp + 1) * N + bn * TN + nq);
            uint4 pv;
            pv.x = pack_h2(w0.x, w1.x);
            pv.y = pack_h2(w0.y, w1.y);
            pv.z = pack_h2(w0.z, w1.z);
            pv.w = pack_h2(w0.w, w1.w);
            *(uint4*)&Bs2[kp][nq] = pv;
        }
        __syncthreads();

#pragma unroll
        for (int kp = 0; kp < KP; kp++) {
            const uint4 a4 = *(const uint4*)&As2[kp][m0];
            const uint4 b4 = *(const uint4*)&Bs2[kp][n0];
            acc[0][0] = fdot2u(a4.x, b4.x, acc[0][0]); acc[0][1] = fdot2u(a4.x, b4.y, acc[0][1]);
            acc[0][2] = fdot2u(a4.x, b4.z, acc[0][2]); acc[0][3] = fdot2u(a4.x, b4.w, acc[0][3]);
            acc[1][0] = fdot2u(a4.y, b4.x, acc[1][0]); acc[1][1] = fdot2u(a4.y, b4.y, acc[1][1]);
            acc[1][2] = fdot2u(a4.y, b4.z, acc[1][2]); acc[1][3] = fdot2u(a4.y, b4.w, acc[1][3]);
            acc[2][0] = fdot2u(a4.z, b4.x, acc[2][0]); acc[2][1] = fdot2u(a4.z, b4.y, acc[2][1]);
            acc[2][2] = fdot2u(a4.z, b4.z, acc[2][2]); acc[2][3] = fdot2u(a4.z, b4.w, acc[2][3]);
            acc[3][0] = fdot2u(a4.w, b4.x, acc[3][0]); acc[3][1] = fdot2u(a4.w, b4.y, acc[3][1]);
            acc[3][2] = fdot2u(a4.w, b4.z, acc[3][2]); acc[3][3] = fdot2u(a4.w, b4.w, acc[3][3]);
        }
        __syncthreads();
    }

    const float4 bv = *(const float4*)(bias + bn * TN + n0);
#pragma unroll
    for (int i = 0; i < 4; i++) {
        float4 v;
        v.x = acc[i][0] + bv.x;
        v.y = acc[i][1] + bv.y;
        v.z = acc[i][2] + bv.z;
        v.w = acc[i][3] + bv.w;
        *(float4*)&C[(size_t)(row0 + m0 + i) * N + bn * TN + n0] = v;
    }
}

// ---------------------------------------------------------------------------
// LSTM recurrence v19: 2-WAY split for HN=256 (layers 0/1).
// r9: exchange-free layer2 runs ~470us vs 705 with 4-way exchange -> the
// 3-sibling exchange chain is ~1100cy of the 3305cy step. 2 blocks per batch
// (halves) shrink it to ONE remote half / ONE sibling: skew tail and poll
// traffic halve; dot issue doubles (WPT 16->32, still 64 VGPR U, v18-proven).
// Also 2-step-ahead xz prefetch (z4a/z4b ping-pong, loop unrolled x2 with a
// macro -- static register names, rule #20): HBM latency ~900cy exceeded the
// 1-step slack ~700cy, stalling each cell phase on vmcnt. INLINE bodies only
// (lambdas demote ur[] to scratch -- r8). Tagged protocol identical; 2-block
// overwrite induction: Y writes slot s tag t+3 only after Y's poll(t+1) read
// X's t+2, which follows X's bar2(t), which follows X's read of Y's t+1.
// ---------------------------------------------------------------------------
__global__ __launch_bounds__(1024, 4) void lstm_half_v19(
    const float* __restrict__ xz,       // [B, T, 1024]
    const float* __restrict__ U,        // [256, 1024]
    float* __restrict__ hout,           // [B, T, 256]
    unsigned int* __restrict__ hbuf)    // [2][B_*256] tagged words
{
    constexpr int HN = 256;
    constexpr int GATES = 1024;
    constexpr int COLS = 512;           // 4 gates x 128 owned units
    constexpr int CP = COLS / 2;        // 256 col-pairs
    constexpr int NKG = 1024 / CP;      // 4 k-groups
    constexpr int KH = HN / NKG;        // 64 k per group
    constexpr int WPT = KH / 2;         // 32 f16-pair words per thread
    constexpr int HOWN = 128;           // units owned by this block
    constexpr int KWORDS = HN / 2;      // 128 hW words (f16 pairs over k)
    constexpr int COLSP = COLS + 2;     // 514

    __shared__ __align__(16) unsigned int hW[KWORDS];
    __shared__ __align__(16) float zpS[NKG * COLSP];

    const int tid = threadIdx.x;
    const int s = blockIdx.x >> 6;      // half 0/1
    const int b = blockIdx.x & 63;      // batch element (sibling 64 apart -> same XCD)

    const int cp = tid % CP;
    const int kq = tid / CP;            // wave-uniform (CP = 256)
    const int c0 = 2 * cp;              // local col (gate*128 + unit_local)
    const int group = c0 / HOWN;        // gate 0..3
    const int gcol = group * HN + s * HOWN + (c0 % HOWN);
    const int wbase = kq * WPT;

    // ---- one-time: U slice into registers (f16-packed over k), then PIN ----
    uint2 ur[WPT];
#pragma unroll
    for (int j = 0; j < WPT; ++j) {
        const int w = wbase + j;
        const float2 r0 = *(const float2*)(U + (size_t)(2 * w) * GATES + gcol);
        const float2 r1 = *(const float2*)(U + (size_t)(2 * w + 1) * GATES + gcol);
        ur[j].x = pack_h2(r0.x, r1.x);
        ur[j].y = pack_h2(r0.y, r1.y);
    }
#pragma unroll
    for (int j = 0; j < WPT; ++j)
        asm volatile("" : "+v"(ur[j].x), "+v"(ur[j].y));

    if (tid < KWORDS) hW[tid] = 0u;     // h_0 = 0
    float cst = 0.f;

    // cell lane: thread u (< 128) owns unit s*128+u; xz col g*256 + s*128 + u
    const float* xzcell = xz + (size_t)b * T_ * GATES + s * HOWN + tid;
    float z4a[4] = {0.f, 0.f, 0.f, 0.f};
    float z4b[4] = {0.f, 0.f, 0.f, 0.f};
    if (tid < HOWN) {
#pragma unroll
        for (int g = 0; g < 4; ++g) z4a[g] = xzcell[g * HN];            // t=0
#pragma unroll
        for (int g = 0; g < 4; ++g) z4b[g] = xzcell[GATES + g * HN];    // t=1
    }
    __syncthreads();   // one-time init barrier

#define V19_STEP(TT, Z)                                                        \
    {                                                                          \
        float acc0 = 0.f, acc1 = 0.f;                                          \
        _Pragma("unroll")                                                      \
        for (int j = 0; j < WPT; j += 4) {                                     \
            const int w = wbase + j;                                           \
            const uint4 hw4 = *(const uint4*)&hW[w];                           \
            acc0 = fdot2u(ur[j + 0].x, hw4.x, acc0); acc1 = fdot2u(ur[j + 0].y, hw4.x, acc1); \
            acc0 = fdot2u(ur[j + 1].x, hw4.y, acc0); acc1 = fdot2u(ur[j + 1].y, hw4.y, acc1); \
            acc0 = fdot2u(ur[j + 2].x, hw4.z, acc0); acc1 = fdot2u(ur[j + 2].y, hw4.z, acc1); \
            acc0 = fdot2u(ur[j + 3].x, hw4.w, acc0); acc1 = fdot2u(ur[j + 3].y, hw4.w, acc1); \
        }                                                                      \
        *(float2*)&zpS[kq * COLSP + c0] = make_float2(acc0, acc1);             \
        bar_lds();                                                             \
        const unsigned int tag = (unsigned int)((TT) + 1);                     \
        unsigned int* hslot = hbuf + (size_t)((TT) & 1) * B_ * HN + b * HN;    \
        if (tid < HOWN) {                                                      \
            float zg[4];                                                       \
            _Pragma("unroll")                                                  \
            for (int g = 0; g < 4; ++g) {                                      \
                float zs = Z[g];                                               \
                _Pragma("unroll")                                              \
                for (int r = 0; r < NKG; ++r) zs += zpS[r * COLSP + g * HOWN + tid]; \
                zg[g] = zs;                                                    \
            }                                                                  \
            if ((TT) + 2 < T_) {                                               \
                _Pragma("unroll")                                              \
                for (int g = 0; g < 4; ++g)                                    \
                    Z[g] = xzcell[(size_t)((TT) + 2) * GATES + g * HN];        \
            }                                                                  \
            const float ig = fsig(zg[0]);                                      \
            const float fg = fsig(zg[1]);                                      \
            const float gg = ftanh(zg[2]);                                     \
            const float og = fsig(zg[3]);                                      \
            cst = fg * cst + ig * gg;                                          \
            const float hnew = og * ftanh(cst);                                \
            hout[((size_t)b * T_ + (TT)) * HN + s * HOWN + tid] = hnew;        \
            if ((TT) < T_ - 1) {                                               \
                const unsigned short h16 = f2h_bits(hnew);                     \
                __hip_atomic_store(&hslot[s * HOWN + tid],                     \
                                   (tag << 16) | (unsigned int)h16,            \
                                   __ATOMIC_RELAXED, __HIP_MEMORY_SCOPE_AGENT);\
                reinterpret_cast<unsigned short*>(hW)[s * HOWN + tid] = h16;   \
            }                                                                  \
        } else if (tid >= 128 && tid < 192 && (TT) < T_ - 1) {                 \
            const int p = (1 - s) * 64 + (tid - 128);  /* remote hW word */    \
            const unsigned long long* hq = (const unsigned long long*)hslot;   \
            unsigned long long v = __hip_atomic_load(&hq[p],                   \
                __ATOMIC_RELAXED, __HIP_MEMORY_SCOPE_AGENT);                   \
            while (((v >> 16) & 0xffffu) != tag || (v >> 48) != tag)           \
                v = __hip_atomic_load(&hq[p],                                  \
                    __ATOMIC_RELAXED, __HIP_MEMORY_SCOPE_AGENT);               \
            hW[p] = (unsigned int)(v & 0xffffu) |                              \
                    ((unsigned int)((v >> 32) & 0xffffu) << 16);               \
        }                                                                      \
        bar_lds();                                                             \
    }

#pragma unroll 1
    for (int t = 0; t < T_; t += 2) {
        V19_STEP(t, z4a)
        V19_STEP(t + 1, z4b)
    }
#undef V19_STEP
}

// ---------------------------------------------------------------------------
// LSTM recurrence v18b: layer 2 (HN=128), ONE block per batch, NO exchange
// (r9: 705 -> ~470us), now + 2-step-ahead xz prefetch (z4a/z4b ping-pong):
// the 1-step prefetch left ~100-300cy of vmcnt stall per cell phase (HBM
// latency ~900cy > bar+dot+bar slack ~700cy).
// ---------------------------------------------------------------------------
__global__ __launch_bounds__(1024, 4) void lstm_full_v18b(
    const float* __restrict__ xz,       // [B, T, 512]
    const float* __restrict__ U,        // [128, 512]
    float* __restrict__ out_last)       // [B, 128]
{
    constexpr int HN = 128;
    constexpr int GATES = 512;
    constexpr int COLS = 512;
    constexpr int CP = COLS / 2;        // 256
    constexpr int NKG = 1024 / CP;      // 4
    constexpr int KH = HN / NKG;        // 32
    constexpr int WPT = KH;             // 32 f32-pair entries
    constexpr int KWORDS = HN;          // 128 f32 h words
    constexpr int COLSP = COLS + 2;

    __shared__ __align__(16) unsigned int hW[KWORDS];
    __shared__ __align__(16) float zpS[NKG * COLSP];

    const int tid = threadIdx.x;
    const int b = blockIdx.x;

    const int cp = tid % CP;
    const int kq = tid / CP;            // wave-uniform
    const int c0 = 2 * cp;
    const int wbase = kq * WPT;

    uint2 ur[WPT];
#pragma unroll
    for (int j = 0; j < WPT; ++j) {
        const int w = wbase + j;
        const float2 r0 = *(const float2*)(U + (size_t)w * GATES + c0);
        ur[j].x = __builtin_bit_cast(unsigned int, r0.x);
        ur[j].y = __builtin_bit_cast(unsigned int, r0.y);
    }
#pragma unroll
    for (int j = 0; j < WPT; ++j)
        asm volatile("" : "+v"(ur[j].x), "+v"(ur[j].y));

    if (tid < KWORDS) hW[tid] = 0u;
    float cst = 0.f;

    const float* xzcell = xz + (size_t)b * T_ * GATES + tid;
    float z4a[4] = {0.f, 0.f, 0.f, 0.f};
    float z4b[4] = {0.f, 0.f, 0.f, 0.f};
    if (tid < HN) {
#pragma unroll
        for (int g = 0; g < 4; ++g) z4a[g] = xzcell[g * HN];            // t=0
#pragma unroll
        for (int g = 0; g < 4; ++g) z4b[g] = xzcell[GATES + g * HN];    // t=1
    }
    __syncthreads();

#define V18_STEP(TT, Z)                                                        \
    {                                                                          \
        float acc0 = 0.f, acc1 = 0.f;                                          \
        _Pragma("unroll")                                                      \
        for (int j = 0; j < WPT; j += 4) {                                     \
            const int w = wbase + j;                                           \
            const uint4 hw4 = *(const uint4*)&hW[w];                           \
            acc0 += ubits(ur[j + 0].x) * ubits(hw4.x); acc1 += ubits(ur[j + 0].y) * ubits(hw4.x); \
            acc0 += ubits(ur[j + 1].x) * ubits(hw4.y); acc1 += ubits(ur[j + 1].y) * ubits(hw4.y); \
            acc0 += ubits(ur[j + 2].x) * ubits(hw4.z); acc1 += ubits(ur[j + 2].y) * ubits(hw4.z); \
            acc0 += ubits(ur[j + 3].x) * ubits(hw4.w); acc1 += ubits(ur[j + 3].y) * ubits(hw4.w); \
        }                                                                      \
        *(float2*)&zpS[kq * COLSP + c0] = make_float2(acc0, acc1);             \
        bar_lds();                                                             \
        if (tid < HN) {                                                        \
            float zg[4];                                                       \
            _Pragma("unroll")                                                  \
            for (int g = 0; g < 4; ++g) {                                      \
                float zs = Z[g];                                               \
                _Pragma("unroll")                                              \
                for (int r = 0; r < NKG; ++r) zs += zpS[r * COLSP + g * HN + tid]; \
                zg[g] = zs;                                                    \
            }                                                                  \
            if ((TT) + 2 < T_) {                                               \
                _Pragma("unroll")                                              \
                for (int g = 0; g < 4; ++g)                                    \
                    Z[g] = xzcell[(size_t)((TT) + 2) * GATES + g * HN];        \
            }                                                                  \
            const float ig = fsig(zg[0]);                                      \
            const float fg = fsig(zg[1]);                                      \
            const float gg = ftanh(zg[2]);                                     \
            const float og = fsig(zg[3]);                                      \
            cst = fg * cst + ig * gg;                                          \
            const float hnew = og * ftanh(cst);                                \
            if ((TT) == T_ - 1) {                                              \
                out_last[(size_t)b * HN + tid] = hnew;                         \
            } else {                                                           \
                hW[tid] = __builtin_bit_cast(unsigned int, hnew);              \
            }                                                                  \
        }                                                                      \
        bar_lds();                                                             \
    }

#pragma unroll 1
    for (int t = 0; t < T_; t += 2) {
        V18_STEP(t, z4a)
        V18_STEP(t + 1, z4b)
    }
#undef V18_STEP
}

// ---------------------------------------------------------------------------
// Launch
// ---------------------------------------------------------------------------
extern "C" void kernel_launch(void* const* d_in, const int* in_sizes, int n_in,
                              void* d_out, int out_size, void* d_ws, size_t ws_size,
                              hipStream_t stream)
{
    const float* x  = (const float*)d_in[0];
    const float* W0 = (const float*)d_in[1];
    const float* U0 = (const float*)d_in[2];
    const float* b0 = (const float*)d_in[3];
    const float* W1 = (const float*)d_in[4];
    const float* U1 = (const float*)d_in[5];
    const float* b1 = (const float*)d_in[6];
    const float* W2 = (const float*)d_in[7];
    const float* U2 = (const float*)d_in[8];
    const float* b2 = (const float*)d_in[9];
    const float* m0 = (const float*)d_in[10];
    const float* m1 = (const float*)d_in[11];
    const float* m2 = (const float*)d_in[12];
    float* out = (float*)d_out;

    // workspace layout:
    //   xz    : 134217728 B   (64*512*1024 floats, reused by all 3 layers)
    //   h0    :  33554432 B
    //   h1    :  33554432 B
    //   hbuf  : 2 regions x 131072 B (2 x 64 x 256 tagged words per layer)
    char* ws = (char*)d_ws;
    float* xz = (float*)ws;
    float* h0 = (float*)(ws + 134217728);
    float* h1 = (float*)(ws + 134217728 + 33554432);
    unsigned int* hb0 = (unsigned int*)(ws + 134217728 + 2 * 33554432);
    unsigned int* hb1 = hb0 + 2 * B_ * 256;

    const int M = B_ * T_;  // 32768

    // Layer 0
    gemm_mask_f16<<<dim3(1024 / 64, M / 64), 256, 0, stream>>>(x, W0, b0, m0, xz, M, 1024, 128);
    lstm_half_v19<<<128, 1024, 0, stream>>>(xz, U0, h0, hb0);

    // Layer 1
    gemm_mask_f16<<<dim3(1024 / 64, M / 64), 256, 0, stream>>>(h0, W1, b1, m1, xz, M, 1024, 256);
    lstm_half_v19<<<128, 1024, 0, stream>>>(xz, U1, h1, hb1);

    // Layer 2 (H=128): one block per batch, NO exchange, deep prefetch
    gemm_mask_f16<<<dim3(512 / 64, M / 64), 256, 0, stream>>>(h1, W2, b2, m2, xz, M, 512, 256);
    lstm_full_v18b<<<64, 1024, 0, stream>>>(xz, U2, out);
}